// Round 1
// baseline (192.756 us; speedup 1.0000x reference)
//
#include <hip/hip_runtime.h>

// DistMult decoder: out[e] = sigmoid( sum_d x[l[e],d] * R[et[e],d] * x[r[e],d] )
// D = 32 floats = 128 B per row. Mapping: 8 lanes per edge, each lane owns one
// float4 (16 B) of the row -> a full 128 B coalesced segment per gathered row,
// the minimum gather granularity. Dot product reduced across the 8-lane group
// with __shfl_xor (masks 1,2,4 stay within an 8-aligned lane group on wave64).

__global__ __launch_bounds__(256) void distmult_kernel(
    const float4* __restrict__ x,    // [N_NODES, 8] as float4
    const float4* __restrict__ R,    // [N_REL, 8] as float4
    const int*    __restrict__ eidx, // [2, E]  (row 0 = left, row 1 = right)
    const int*    __restrict__ etype,// [E]
    float*        __restrict__ out,  // [E]
    int E)
{
    const int tid = blockIdx.x * blockDim.x + threadIdx.x;
    const int e   = tid >> 3;      // 8 lanes per edge
    const int d4  = tid & 7;       // which float4 of the 32-float row
    if (e >= E) return;

    // All 8 lanes of a group load the same index -> same-address broadcast.
    const int l = eidx[e];
    const int r = eidx[E + e];
    const int t = etype[e];

    const float4 a = x[l * 8 + d4];
    const float4 b = x[r * 8 + d4];
    const float4 c = R[t * 8 + d4];

    float s = a.x * c.x * b.x;
    s = fmaf(a.y * c.y, b.y, s);
    s = fmaf(a.z * c.z, b.z, s);
    s = fmaf(a.w * c.w, b.w, s);

    // Reduce across the 8-lane group (xor of bits 0..2 stays in-group).
    s += __shfl_xor(s, 1);
    s += __shfl_xor(s, 2);
    s += __shfl_xor(s, 4);

    if (d4 == 0) {
        // sigmoid(s) = 1 / (1 + e^-s)
        out[e] = __builtin_amdgcn_rcpf(1.0f + __expf(-s));
    }
}

extern "C" void kernel_launch(void* const* d_in, const int* in_sizes, int n_in,
                              void* d_out, int out_size, void* d_ws, size_t ws_size,
                              hipStream_t stream) {
    const float* x     = (const float*)d_in[0];
    const float* R     = (const float*)d_in[1];
    const int*   eidx  = (const int*)d_in[2];
    const int*   etype = (const int*)d_in[3];
    float*       out   = (float*)d_out;

    const int E = in_sizes[3];            // 4,000,000 edges
    const long long threads = (long long)E * 8;
    const int block = 256;
    const int grid  = (int)((threads + block - 1) / block);

    distmult_kernel<<<grid, block, 0, stream>>>(
        (const float4*)x, (const float4*)R, eidx, etype, out, E);
}

// Round 2
// 188.232 us; speedup vs baseline: 1.0240x; 1.0240x over previous
//
#include <hip/hip_runtime.h>

// DistMult decoder: out[e] = sigmoid( sum_d x[l[e],d] * R[et[e],d] * x[r[e],d] )
// D = 32 floats = 128 B/row. Mapping: 8 lanes per group, each group handles
// FOUR consecutive edges. Indices for the 4 edges come in as one int4 load per
// array; then 12 independent float4 gathers (4 edges x {xl, xr, R}) are issued
// back-to-back to maximize memory-level parallelism (the R0 kernel was
// latency-bound: only 3 outstanding gathers/wave, 44% of HBM-path BW).
// Reduction: 3 x __shfl_xor per edge (masks 1,2,4 stay in the 8-lane group).
// Lane 0 of each group writes a coalesced float4 of sigmoids.

__global__ __launch_bounds__(256) void distmult_kernel(
    const float4* __restrict__ x,    // [N_NODES, 8] as float4
    const float4* __restrict__ R,    // [N_REL, 8] as float4
    const int*    __restrict__ eidx, // [2, E]
    const int*    __restrict__ etype,// [E]
    float*        __restrict__ out,  // [E]
    int E)
{
    const int tid = blockIdx.x * blockDim.x + threadIdx.x;
    const int g   = tid >> 3;       // 8-lane group id
    const int d4  = tid & 7;        // which float4 of the 32-float row
    const int e0  = g << 2;         // first of this group's 4 edges
    if (e0 >= E) return;

    if (e0 + 4 <= E) {
        // Index loads: all 8 lanes of the group load the same 16 B -> broadcast.
        const int4 l4 = *(const int4*)(eidx + e0);
        const int4 r4 = *(const int4*)(eidx + E + e0);
        const int4 t4 = *(const int4*)(etype + e0);

        // 12 independent gathers, issued before any dependent math.
        const float4 a0 = x[l4.x * 8 + d4];
        const float4 a1 = x[l4.y * 8 + d4];
        const float4 a2 = x[l4.z * 8 + d4];
        const float4 a3 = x[l4.w * 8 + d4];
        const float4 b0 = x[r4.x * 8 + d4];
        const float4 b1 = x[r4.y * 8 + d4];
        const float4 b2 = x[r4.z * 8 + d4];
        const float4 b3 = x[r4.w * 8 + d4];
        const float4 c0 = R[t4.x * 8 + d4];
        const float4 c1 = R[t4.y * 8 + d4];
        const float4 c2 = R[t4.z * 8 + d4];
        const float4 c3 = R[t4.w * 8 + d4];

        float s0 = a0.x * c0.x * b0.x;
        s0 = fmaf(a0.y * c0.y, b0.y, s0);
        s0 = fmaf(a0.z * c0.z, b0.z, s0);
        s0 = fmaf(a0.w * c0.w, b0.w, s0);
        float s1 = a1.x * c1.x * b1.x;
        s1 = fmaf(a1.y * c1.y, b1.y, s1);
        s1 = fmaf(a1.z * c1.z, b1.z, s1);
        s1 = fmaf(a1.w * c1.w, b1.w, s1);
        float s2 = a2.x * c2.x * b2.x;
        s2 = fmaf(a2.y * c2.y, b2.y, s2);
        s2 = fmaf(a2.z * c2.z, b2.z, s2);
        s2 = fmaf(a2.w * c2.w, b2.w, s2);
        float s3 = a3.x * c3.x * b3.x;
        s3 = fmaf(a3.y * c3.y, b3.y, s3);
        s3 = fmaf(a3.z * c3.z, b3.z, s3);
        s3 = fmaf(a3.w * c3.w, b3.w, s3);

        s0 += __shfl_xor(s0, 1); s0 += __shfl_xor(s0, 2); s0 += __shfl_xor(s0, 4);
        s1 += __shfl_xor(s1, 1); s1 += __shfl_xor(s1, 2); s1 += __shfl_xor(s1, 4);
        s2 += __shfl_xor(s2, 1); s2 += __shfl_xor(s2, 2); s2 += __shfl_xor(s2, 4);
        s3 += __shfl_xor(s3, 1); s3 += __shfl_xor(s3, 2); s3 += __shfl_xor(s3, 4);

        if (d4 == 0) {
            float4 o;
            o.x = __builtin_amdgcn_rcpf(1.0f + __expf(-s0));
            o.y = __builtin_amdgcn_rcpf(1.0f + __expf(-s1));
            o.z = __builtin_amdgcn_rcpf(1.0f + __expf(-s2));
            o.w = __builtin_amdgcn_rcpf(1.0f + __expf(-s3));
            *(float4*)(out + e0) = o;
        }
    } else {
        // Tail (not hit for E divisible by 4, kept for safety).
        for (int e = e0; e < E; ++e) {
            const int l = eidx[e];
            const int r = eidx[E + e];
            const int t = etype[e];
            const float4 a = x[l * 8 + d4];
            const float4 b = x[r * 8 + d4];
            const float4 c = R[t * 8 + d4];
            float s = a.x * c.x * b.x;
            s = fmaf(a.y * c.y, b.y, s);
            s = fmaf(a.z * c.z, b.z, s);
            s = fmaf(a.w * c.w, b.w, s);
            s += __shfl_xor(s, 1); s += __shfl_xor(s, 2); s += __shfl_xor(s, 4);
            if (d4 == 0) out[e] = __builtin_amdgcn_rcpf(1.0f + __expf(-s));
        }
    }
}

extern "C" void kernel_launch(void* const* d_in, const int* in_sizes, int n_in,
                              void* d_out, int out_size, void* d_ws, size_t ws_size,
                              hipStream_t stream) {
    const float* x     = (const float*)d_in[0];
    const float* R     = (const float*)d_in[1];
    const int*   eidx  = (const int*)d_in[2];
    const int*   etype = (const int*)d_in[3];
    float*       out   = (float*)d_out;

    const int E = in_sizes[3];                       // 4,000,000 edges
    const long long groups  = ((long long)E + 3) / 4;
    const long long threads = groups * 8;
    const int block = 256;
    const int grid  = (int)((threads + block - 1) / block);

    distmult_kernel<<<grid, block, 0, stream>>>(
        (const float4*)x, (const float4*)R, eidx, etype, out, E);
}

// Round 3
// 160.256 us; speedup vs baseline: 1.2028x; 1.1746x over previous
//
#include <hip/hip_runtime.h>

// DistMult decoder: out[e] = sigmoid( sum_d x[l,d] * R[et,d] * x[r,d] )
//
// R2 structure: two kernels.
//  A) convert x (100k x 32 fp32, 12.8 MB) -> fp16 rows in d_ws (6.4 MB).
//     Rationale: R1 showed the kernel is bound by L2-miss gather traffic
//     (FETCH 374 MB @ 3.8 TB/s == dur). fp16 halves every gathered row
//     (64 B) and lets x nearly fit the 4 MiB per-XCD L2.
//  B) gather kernel: 8 lanes/edge, lane holds 4 dims. xl/xr rows read as
//     8 B half4 (dense 64 B/row), R read as fp32 float4 (L1-hot, sorted
//     edge_type). 4-edge unroll per group keeps 12 independent gathers in
//     flight. 3x shfl_xor reduction, lane0 writes float4 of sigmoids.
// Accuracy: fp16 on x only -> score err ~0.006 std, sigmoid err << 2e-2.

typedef _Float16 half4 __attribute__((ext_vector_type(4)));

__global__ __launch_bounds__(256) void convert_x_kernel(
    const float4* __restrict__ x, half4* __restrict__ xh, int n4)
{
    int i = blockIdx.x * blockDim.x + threadIdx.x;
    if (i >= n4) return;
    float4 v = x[i];
    half4 h;
    h.x = (_Float16)v.x; h.y = (_Float16)v.y;
    h.z = (_Float16)v.z; h.w = (_Float16)v.w;
    xh[i] = h;
}

__global__ __launch_bounds__(256) void distmult_kernel(
    const half4*  __restrict__ xh,   // [N_NODES, 8] as half4 (64 B rows)
    const float4* __restrict__ R,    // [N_REL, 8] as float4 (128 B rows)
    const int*    __restrict__ eidx, // [2, E]
    const int*    __restrict__ etype,// [E]
    float*        __restrict__ out,  // [E]
    int E)
{
    const int tid = blockIdx.x * blockDim.x + threadIdx.x;
    const int g   = tid >> 3;       // 8-lane group id
    const int d4  = tid & 7;        // which 4-dim chunk of the 32-dim row
    const int e0  = g << 2;         // first of this group's 4 edges
    if (e0 >= E) return;

    if (e0 + 4 <= E) {
        const int4 l4 = *(const int4*)(eidx + e0);
        const int4 r4 = *(const int4*)(eidx + E + e0);
        const int4 t4 = *(const int4*)(etype + e0);

        // 12 independent gathers (8x 8B half4 + 4x 16B float4), issued
        // before any dependent math.
        const half4 a0 = xh[l4.x * 8 + d4];
        const half4 a1 = xh[l4.y * 8 + d4];
        const half4 a2 = xh[l4.z * 8 + d4];
        const half4 a3 = xh[l4.w * 8 + d4];
        const half4 b0 = xh[r4.x * 8 + d4];
        const half4 b1 = xh[r4.y * 8 + d4];
        const half4 b2 = xh[r4.z * 8 + d4];
        const half4 b3 = xh[r4.w * 8 + d4];
        const float4 c0 = R[t4.x * 8 + d4];
        const float4 c1 = R[t4.y * 8 + d4];
        const float4 c2 = R[t4.z * 8 + d4];
        const float4 c3 = R[t4.w * 8 + d4];

        float s0 = (float)a0.x * c0.x * (float)b0.x;
        s0 = fmaf((float)a0.y * c0.y, (float)b0.y, s0);
        s0 = fmaf((float)a0.z * c0.z, (float)b0.z, s0);
        s0 = fmaf((float)a0.w * c0.w, (float)b0.w, s0);
        float s1 = (float)a1.x * c1.x * (float)b1.x;
        s1 = fmaf((float)a1.y * c1.y, (float)b1.y, s1);
        s1 = fmaf((float)a1.z * c1.z, (float)b1.z, s1);
        s1 = fmaf((float)a1.w * c1.w, (float)b1.w, s1);
        float s2 = (float)a2.x * c2.x * (float)b2.x;
        s2 = fmaf((float)a2.y * c2.y, (float)b2.y, s2);
        s2 = fmaf((float)a2.z * c2.z, (float)b2.z, s2);
        s2 = fmaf((float)a2.w * c2.w, (float)b2.w, s2);
        float s3 = (float)a3.x * c3.x * (float)b3.x;
        s3 = fmaf((float)a3.y * c3.y, (float)b3.y, s3);
        s3 = fmaf((float)a3.z * c3.z, (float)b3.z, s3);
        s3 = fmaf((float)a3.w * c3.w, (float)b3.w, s3);

        s0 += __shfl_xor(s0, 1); s0 += __shfl_xor(s0, 2); s0 += __shfl_xor(s0, 4);
        s1 += __shfl_xor(s1, 1); s1 += __shfl_xor(s1, 2); s1 += __shfl_xor(s1, 4);
        s2 += __shfl_xor(s2, 1); s2 += __shfl_xor(s2, 2); s2 += __shfl_xor(s2, 4);
        s3 += __shfl_xor(s3, 1); s3 += __shfl_xor(s3, 2); s3 += __shfl_xor(s3, 4);

        if (d4 == 0) {
            float4 o;
            o.x = __builtin_amdgcn_rcpf(1.0f + __expf(-s0));
            o.y = __builtin_amdgcn_rcpf(1.0f + __expf(-s1));
            o.z = __builtin_amdgcn_rcpf(1.0f + __expf(-s2));
            o.w = __builtin_amdgcn_rcpf(1.0f + __expf(-s3));
            *(float4*)(out + e0) = o;
        }
    } else {
        for (int e = e0; e < E; ++e) {
            const int l = eidx[e];
            const int r = eidx[E + e];
            const int t = etype[e];
            const half4 a = xh[l * 8 + d4];
            const half4 b = xh[r * 8 + d4];
            const float4 c = R[t * 8 + d4];
            float s = (float)a.x * c.x * (float)b.x;
            s = fmaf((float)a.y * c.y, (float)b.y, s);
            s = fmaf((float)a.z * c.z, (float)b.z, s);
            s = fmaf((float)a.w * c.w, (float)b.w, s);
            s += __shfl_xor(s, 1); s += __shfl_xor(s, 2); s += __shfl_xor(s, 4);
            if (d4 == 0) out[e] = __builtin_amdgcn_rcpf(1.0f + __expf(-s));
        }
    }
}

extern "C" void kernel_launch(void* const* d_in, const int* in_sizes, int n_in,
                              void* d_out, int out_size, void* d_ws, size_t ws_size,
                              hipStream_t stream) {
    const float* x     = (const float*)d_in[0];
    const float* R     = (const float*)d_in[1];
    const int*   eidx  = (const int*)d_in[2];
    const int*   etype = (const int*)d_in[3];
    float*       out   = (float*)d_out;

    const int E   = in_sizes[3];          // 4,000,000 edges
    const int n4  = in_sizes[0] / 4;      // x element count / 4 (float4 units)
    half4* xh = (half4*)d_ws;             // 6.4 MB fp16 copy of x

    convert_x_kernel<<<(n4 + 255) / 256, 256, 0, stream>>>(
        (const float4*)x, xh, n4);

    const long long groups  = ((long long)E + 3) / 4;
    const long long threads = groups * 8;
    const int block = 256;
    const int grid  = (int)((threads + block - 1) / block);

    distmult_kernel<<<grid, block, 0, stream>>>(
        xh, (const float4*)R, eidx, etype, out, E);
}